// Round 13
// baseline (555.031 us; speedup 1.0000x reference)
//
#include <hip/hip_runtime.h>
#include <stdint.h>

static constexpr int Bn = 16, Tn = 2048, En = 1024, NHn = 16, HDn = 64, NLEVn = 12;

typedef __attribute__((ext_vector_type(8))) short short8;
typedef __attribute__((ext_vector_type(4))) float floatx4;

__device__ __forceinline__ unsigned short f2bf(float f) {
  unsigned int u = __float_as_uint(f);
  u += 0x7fffu + ((u >> 16) & 1u);
  return (unsigned short)(u >> 16);
}
__device__ __forceinline__ float bf2f(unsigned short s) {
  return __uint_as_float(((unsigned int)s) << 16);
}

__device__ __forceinline__ void async16(const unsigned short* g, unsigned short* l) {
  __builtin_amdgcn_global_load_lds(
      (const __attribute__((address_space(1))) unsigned int*)g,
      (__attribute__((address_space(3))) unsigned int*)l, 16, 0, 0);
}

// ---------------- fused pre-pass: scan (blocks 0..15) + all fp32->bf16 cvts ----------------
static constexpr int NX4 = Bn * Tn * En / 4;   // 8,388,608
static constexpr int NW4 = En * En / 4;        // 262,144

__global__ void k_pre(const float* __restrict__ x, unsigned short* __restrict__ xb,
                      const float* __restrict__ Wv, unsigned short* __restrict__ Wvb,
                      const float* __restrict__ Wo, unsigned short* __restrict__ Wob,
                      const float* __restrict__ A_log, const float* __restrict__ A_bias,
                      float* __restrict__ csT) {
  int blk = blockIdx.x;
  int tid = threadIdx.x;
  if (blk < 16) {
    // ---- per-head prefix scan of log(sigmoid(A)) -> csT[h][t] ----
    int h = blk;
    __shared__ float part[256];
    float loc[8];
    float run = 0.f;
#pragma unroll
    for (int j = 0; j < 8; j++) {
      int t = tid * 8 + j;
      float xx = A_log[t * NHn + h] + A_bias[t * NHn + h];
      float ls = -log1pf(__expf(-xx));
      run += ls;
      loc[j] = run;
    }
    part[tid] = run;
    __syncthreads();
    for (int d = 1; d < 256; d <<= 1) {
      float v = (tid >= d) ? part[tid - d] : 0.f;
      __syncthreads();
      part[tid] += v;
      __syncthreads();
    }
    float off = (tid > 0) ? part[tid - 1] : 0.f;
#pragma unroll
    for (int j = 0; j < 8; j++) csT[(size_t)h * Tn + tid * 8 + j] = loc[j] + off;
    return;
  }
  int i = (blk - 16) * 256 + tid;
  const float* src;
  unsigned short* dst;
  int base;
  if (i < NX4) { src = x; dst = xb; base = 0; }
  else if (i < NX4 + NW4) { src = Wv; dst = Wvb; base = NX4; }
  else if (i < NX4 + 2 * NW4) { src = Wo; dst = Wob; base = NX4 + NW4; }
  else return;
  int k = i - base;
  float4 v = ((const float4*)src)[k];
  ushort4 o;
  o.x = f2bf(v.x); o.y = f2bf(v.y); o.z = f2bf(v.z); o.w = f2bf(v.w);
  ((ushort4*)dst)[k] = o;
}

// ---------------- v-suffix-sums: Stail[h][mt][col] = sum_{s>=256(mt+1)} v ----------------
__global__ void k_tail(const unsigned short* __restrict__ vt, float* __restrict__ Stail) {
  int row = blockIdx.x;            // h*1024 + col, col=(b<<6)|d
  int tid = threadIdx.x;
  __shared__ float C[8];
  short8 v = *(const short8*)&vt[(size_t)row * Tn + tid * 8];
  float p = 0.f;
#pragma unroll
  for (int e = 0; e < 8; e++) p += bf2f((unsigned short)v[e]);
#pragma unroll
  for (int o = 16; o > 0; o >>= 1) p += __shfl_xor(p, o, 64);
  if ((tid & 31) == 0) C[tid >> 5] = p;
  __syncthreads();
  if (tid < 8) {
    float s = 0.f;
    for (int k = tid + 1; k < 8; k++) s += C[k];
    int h = row >> 10, col = row & 1023;
    Stail[(size_t)h * 8192 + tid * 1024 + col] = s;
  }
}

// ================= FUSED: gemm_v (blk%3==2) + weights (blk%3<2), 512 threads =================
// gemm_v: v = x@Wv^T + bv, 256x128 tile, fused transpose -> vt[h][b][d][t].
// weights: P[h][t][s] for s < Bt = 256*(t/256+1); denom += (Tn-Bt) for the
// analytic all-ones tail. Independent inputs (weights needs only csT/L/levels),
// disjoint outputs (Pw un-aliased), so the two roles co-run: MFMA pipe (gemm_v)
// and exp/VALU pipe (weights) overlap on each CU (1 block of each at 116 VGPR).
__global__ __launch_bounds__(512)
void k_gvw(const unsigned short* __restrict__ A, const unsigned short* __restrict__ Bm,
           const float* __restrict__ bias, unsigned short* __restrict__ vt,
           const float* __restrict__ L, const float* __restrict__ Lb,
           const int* __restrict__ levels, const float* __restrict__ csT,
           unsigned short* __restrict__ P, float* __restrict__ denom) {
  __shared__ unsigned short smem[24576];     // gemm_v: 48KB stage; weights: ~1KB floats
  int blk = blockIdx.x;
  int tid = threadIdx.x;

  if (blk % 3 != 2) {
    // ---------------- weights role: t = (blk/3)*2 + blk%3 ----------------
    int t = (blk / 3) * 2 + (blk % 3);
    float* sm = (float*)smem;
    float* Lrow = sm;            // 192
    float* cst  = sm + 192;      // 16
    float* dsum = sm + 208;      // 16
    if (tid < NHn * NLEVn) Lrow[tid] = L[t * NHn * NLEVn + tid] + Lb[t * NHn * NLEVn + tid];
    if (tid < NHn) { cst[tid] = csT[(size_t)tid * Tn + t]; dsum[tid] = 0.f; }
    __syncthreads();
    int Bt = ((t >> 8) + 1) << 8;
    float acc[NHn];
#pragma unroll
    for (int h = 0; h < NHn; h++) acc[h] = 0.f;
    for (int s = tid; s < Bt; s += 512) {
      int lev = levels[(size_t)t * Tn + s];
      bool causal = (s <= t);
#pragma unroll
      for (int h = 0; h < NHn; h++) {
        float w = 1.f;   // exp(0) for s > t
        if (causal) {
          float csr = csT[(size_t)h * Tn + s];      // coalesced: 4 B/lane
          float dec = __expf(cst[h] - csr);
          w = __expf(Lrow[h * NLEVn + lev] * dec);
        }
        unsigned short pb = f2bf(w);
        acc[h] += bf2f(pb);
        P[((size_t)h * Tn + t) * Tn + s] = pb;
      }
    }
    int lane = tid & 63;
#pragma unroll
    for (int h = 0; h < NHn; h++) {
      float v = acc[h];
      for (int o = 32; o > 0; o >>= 1) v += __shfl_down(v, o, 64);
      if (lane == 0) atomicAdd(&dsum[h], v);
    }
    __syncthreads();
    if (tid < NHn) denom[(size_t)tid * Tn + t] = dsum[tid] + (float)(Tn - Bt);
    return;
  }

  // ---------------- gemm_v role: flat = blk/3 in [0,1024) ----------------
  unsigned short* As = smem;                 // 256 x 64
  unsigned short* Bs = smem + 16384;         // 128 x 64
  const int K = 1024;
  int wave = tid >> 6, lane = tid & 63;
  int wm = wave >> 1, wn = wave & 1;         // 4 x 2 waves of 64x64 tiles

  int flat = blk / 3;                        // consecutive -> round-robin XCDs
  int xcd = flat & 7, slot = flat >> 3;      // slot 0..127
  int strip = xcd * 16 + (slot >> 3);        // 128 strips, 16 per XCD
  int nt = slot & 7;
  int bm = strip * 256, bn = nt * 128;

  floatx4 zero4 = {0.f, 0.f, 0.f, 0.f};
  floatx4 acc[4][4];
#pragma unroll
  for (int i = 0; i < 4; i++)
#pragma unroll
    for (int j = 0; j < 4; j++) acc[i][j] = zero4;

  for (int k0 = 0; k0 < K; k0 += 64) {
    __syncthreads();
#pragma unroll
    for (int j = 0; j < 4; j++) {            // A: 256 rows x 64 k (32KB)
      int f = j * 512 + tid;
      int r = f >> 3, c = f & 7;
      int cg = c ^ (r & 7);
      async16(&A[(size_t)(bm + r) * K + k0 + cg * 8], &As[f * 8]);
    }
#pragma unroll
    for (int j = 0; j < 2; j++) {            // B: 128 rows x 64 k (16KB)
      int f = j * 512 + tid;
      int r = f >> 3, c = f & 7;
      int cg = c ^ (r & 7);
      async16(&Bm[(size_t)(bn + r) * K + k0 + cg * 8], &Bs[f * 8]);
    }
    __syncthreads();
#pragma unroll
    for (int kk = 0; kk < 2; kk++) {
      short8 af[4], bfr[4];
      int cgk = kk * 4 + (lane >> 4);
#pragma unroll
      for (int i = 0; i < 4; i++) {
        int m = wm * 64 + i * 16 + (lane & 15);
        af[i] = *(const short8*)&As[m * 64 + ((cgk ^ (m & 7)) * 8)];
        int n = wn * 64 + i * 16 + (lane & 15);
        bfr[i] = *(const short8*)&Bs[n * 64 + ((cgk ^ (n & 7)) * 8)];
      }
#pragma unroll
      for (int i = 0; i < 4; i++)
#pragma unroll
        for (int j = 0; j < 4; j++)
          acc[i][j] = __builtin_amdgcn_mfma_f32_16x16x32_bf16(af[i], bfr[j], acc[i][j], 0, 0, 0);
    }
  }

  // ---- fused transpose epilogue: write vt[h][b][d][t] ----
  int b = bm >> 11, t0 = bm & 2047;
  unsigned short* Ct = smem;                 // 64 cols x (256+8) rows
  const int S = 264;
#pragma unroll 1
  for (int pass = 0; pass < 2; pass++) {
    __syncthreads();
    if (wn == pass) {
#pragma unroll
      for (int i = 0; i < 4; i++) {
#pragma unroll
        for (int j = 0; j < 4; j++) {
          int colL = j * 16 + (lane & 15);
          float bia = bias[bn + pass * 64 + colL];
          int rowb = wm * 64 + i * 16 + (lane >> 4) * 4;
          ushort4 p;
          p.x = f2bf(acc[i][j][0] + bia);
          p.y = f2bf(acc[i][j][1] + bia);
          p.z = f2bf(acc[i][j][2] + bia);
          p.w = f2bf(acc[i][j][3] + bia);
          *(ushort4*)&Ct[colL * S + rowb] = p;
        }
      }
    }
    __syncthreads();
#pragma unroll
    for (int cc = 0; cc < 4; cc++) {
      int colL = wave * 8 + cc * 2 + (lane >> 5);
      int gc = bn + pass * 64 + colL;
      int h = gc >> 6, d = gc & 63;
      int tt = (lane & 31) * 8;
      short8 v = *(const short8*)&Ct[colL * S + tt];
      *(short8*)&vt[((size_t)((h * Bn + b) * HDn + d)) * Tn + t0 + tt] = v;
    }
  }
}

// ================= shared 256x256 BK=64 macros (round-2 verified) =================

#define STAGE_A(kt, half, buf)                                                   \
  {                                                                              \
    _Pragma("unroll")                                                            \
    for (int j_ = 0; j_ < 2; j_++) {                                             \
      int f_ = j_ * 512 + tid;                                                   \
      int r_ = f_ >> 3, c_ = f_ & 7;                                             \
      int cg_ = c_ ^ (r_ & 7);                                                   \
      async16(&Ap[(size_t)(bm + (half) * 128 + r_) * K + (kt) * 64 + cg_ * 8],   \
              &smem[(buf) * 32768 + ((half) * 128 + r_) * 64 + c_ * 8]);         \
    }                                                                            \
  }

#define STAGE_B(kt, half, buf)                                                   \
  {                                                                              \
    _Pragma("unroll")                                                            \
    for (int j_ = 0; j_ < 2; j_++) {                                             \
      int f_ = j_ * 512 + tid;                                                   \
      int r_ = f_ >> 3, c_ = f_ & 7;                                             \
      int cg_ = c_ ^ (r_ & 7);                                                   \
      async16(&Bp[(size_t)(bn + (half) * 128 + r_) * K + (kt) * 64 + cg_ * 8],   \
              &smem[(buf) * 32768 + 16384 + ((half) * 128 + r_) * 64 + c_ * 8]); \
    }                                                                            \
  }

#define LOAD_A(buf, Mh)                                                          \
  {                                                                              \
    _Pragma("unroll")                                                            \
    for (int ii_ = 0; ii_ < 4; ii_++) {                                          \
      int m_ = (Mh) * 128 + wm * 64 + ii_ * 16 + (lane & 15);                    \
      _Pragma("unroll")                                                          \
      for (int kk_ = 0; kk_ < 2; kk_++) {                                        \
        int cgk_ = kk_ * 4 + (lane >> 4);                                        \
        aR[ii_][kk_] =                                                           \
            *(const short8*)&smem[(buf) * 32768 + m_ * 64 + ((cgk_ ^ (m_ & 7)) * 8)]; \
      }                                                                          \
    }                                                                            \
  }

#define LOAD_B(buf, Nh)                                                          \
  {                                                                              \
    _Pragma("unroll")                                                            \
    for (int jj_ = 0; jj_ < 2; jj_++) {                                          \
      int n_ = (Nh) * 128 + wn * 32 + jj_ * 16 + (lane & 15);                    \
      _Pragma("unroll")                                                          \
      for (int kk_ = 0; kk_ < 2; kk_++) {                                        \
        int cgk_ = kk_ * 4 + (lane >> 4);                                        \
        bR[jj_][kk_] = *(const short8*)&smem[(buf) * 32768 + 16384 + n_ * 64 +   \
                                             ((cgk_ ^ (n_ & 7)) * 8)];           \
      }                                                                          \
    }                                                                            \
  }

#define MFMA16(Mh, Nh)                                                           \
  {                                                                              \
    __builtin_amdgcn_s_setprio(1);                                               \
    _Pragma("unroll")                                                            \
    for (int kk_ = 0; kk_ < 2; kk_++)                                            \
      _Pragma("unroll")                                                          \
      for (int ii_ = 0; ii_ < 4; ii_++)                                          \
        _Pragma("unroll")                                                        \
        for (int jj_ = 0; jj_ < 2; jj_++)                                        \
          acc[(Mh) * 4 + ii_][(Nh) * 2 + jj_] = __builtin_amdgcn_mfma_f32_16x16x32_bf16( \
              aR[ii_][kk_], bR[jj_][kk_], acc[(Mh) * 4 + ii_][(Nh) * 2 + jj_], 0, 0, 0); \
    __builtin_amdgcn_s_setprio(0);                                               \
  }

#define WAIT6 asm volatile("s_waitcnt vmcnt(6)" ::: "memory")
#define BAR                                                                      \
  {                                                                              \
    asm volatile("" ::: "memory");                                               \
    __builtin_amdgcn_s_barrier();                                                \
    asm volatile("" ::: "memory");                                               \
  }

#define KTILE_BODY(buf, nbuf, tn)                                                \
  {                                                                              \
    STAGE_A(tn, 0, nbuf);                                                        \
    WAIT6; BAR;                                                                  \
    LOAD_A(buf, 0);                                                              \
    LOAD_B(buf, 0);                                                              \
    MFMA16(0, 0);                                                                \
    BAR;                                                                         \
    STAGE_B(tn, 0, nbuf);                                                        \
    WAIT6; BAR;                                                                  \
    LOAD_B(buf, 1);                                                              \
    MFMA16(0, 1);                                                                \
    BAR;                                                                         \
    STAGE_B(tn, 1, nbuf);                                                        \
    WAIT6; BAR;                                                                  \
    LOAD_A(buf, 1);                                                              \
    MFMA16(1, 1);                                                                \
    BAR;                                                                         \
    STAGE_A(tn, 1, nbuf);                                                        \
    WAIT6; BAR;                                                                  \
    LOAD_B(buf, 0);                                                              \
    MFMA16(1, 0);                                                                \
    BAR;                                                                         \
  }

// ================= GEMM 2: attn @ v (per head), causal-range K-loop =================
__global__ __launch_bounds__(512, 2)
void k_gemm_attn(const unsigned short* __restrict__ P, const unsigned short* __restrict__ vt,
                 const float* __restrict__ denom, const float* __restrict__ Stail,
                 unsigned short* __restrict__ outp) {
  __shared__ unsigned short smem[65536];     // 128 KiB: 2 x (A 256x64 | B 256x64)
  const int K = Tn;
  int tid = threadIdx.x;
  int wave = tid >> 6, lane = tid & 63;
  int wm = wave >> 2, wn = wave & 3;         // per-quadrant: 2x4 waves of 64x32

  int flat = blockIdx.y * 8 + blockIdx.x;    // gridDim = (8, 64)
  int xcd = flat & 7, slot = flat >> 3;      // slot 0..63 within XCD
  int h = xcd * 2 + (slot >> 5);             // 2 heads per XCD
  int mtraw = (slot >> 2) & 7;
  int mt = (slot & 32) ? (7 - mtraw) : mtraw;  // complementary-mt pairing
  int nt = slot & 3;
  int bm = mt * 256, bn = nt * 256;

  const unsigned short* Ap = P + (size_t)h * Tn * Tn;
  const unsigned short* Bp = vt + (size_t)h * (Bn * HDn) * Tn;

  floatx4 zero4 = {0.f, 0.f, 0.f, 0.f};
  floatx4 acc[8][4];
#pragma unroll
  for (int i = 0; i < 8; i++)
#pragma unroll
    for (int j = 0; j < 4; j++) acc[i][j] = zero4;

  short8 aR[4][2], bR[2][2];

  STAGE_A(0, 0, 0);
  STAGE_B(0, 0, 0);
  STAGE_B(0, 1, 0);
  STAGE_A(0, 1, 0);

  const int nkb = 4 * (mt + 1);              // causal K-tiles only
  for (int t = 0; t < nkb; t++) {
    int buf = t & 1, nbuf = buf ^ 1;
    int tn = (t < nkb - 1) ? t + 1 : nkb - 1;
    KTILE_BODY(buf, nbuf, tn);
  }
  asm volatile("s_waitcnt vmcnt(0)" ::: "memory");

  float tl[4];
#pragma unroll
  for (int j = 0; j < 4; j++) {
    int col = bn + (j >> 1) * 128 + wn * 32 + (j & 1) * 16 + (lane & 15);
    tl[j] = Stail[(size_t)h * 8192 + mt * 1024 + col];
  }

#pragma unroll
  for (int i = 0; i < 8; i++) {
    int rb = bm + (i >> 2) * 128 + wm * 64 + (i & 3) * 16 + (lane >> 4) * 4;
#pragma unroll
    for (int r = 0; r < 4; r++) {
      int row = rb + r;
      float sc = 1.f / denom[(size_t)h * Tn + row];
#pragma unroll
      for (int j = 0; j < 4; j++) {
        int col = bn + (j >> 1) * 128 + wn * 32 + (j & 1) * 16 + (lane & 15);
        int b = col >> 6, d = col & 63;
        outp[((size_t)(b * Tn + row)) * En + h * HDn + d] = f2bf((acc[i][j][r] + tl[j]) * sc);
      }
    }
  }
}

// ================= GEMM 3: out = o@Wo^T + bo, 256x256 block (round-2 skeleton) =================
__global__ __launch_bounds__(512, 2)
void k_gemm_out(const unsigned short* __restrict__ A, const unsigned short* __restrict__ Bm,
                const float* __restrict__ bias, float* __restrict__ out) {
  __shared__ unsigned short smem[65536];     // 128 KiB
  const int K = 1024, N = 1024;
  int tid = threadIdx.x;
  int wave = tid >> 6, lane = tid & 63;
  int wm = wave >> 2, wn = wave & 3;

  int flat = blockIdx.y * 8 + blockIdx.x;    // gridDim = (8, 64)
  int wg = (flat & 7) * 64 + (flat >> 3);    // 512 blocks: 128 mt x 4 nt
  int mt = wg >> 2, nt = wg & 3;
  int bm = mt * 256, bn = nt * 256;

  const unsigned short* Ap = A;
  const unsigned short* Bp = Bm;

  floatx4 zero4 = {0.f, 0.f, 0.f, 0.f};
  floatx4 acc[8][4];
#pragma unroll
  for (int i = 0; i < 8; i++)
#pragma unroll
    for (int j = 0; j < 4; j++) acc[i][j] = zero4;

  short8 aR[4][2], bR[2][2];

  STAGE_A(0, 0, 0);
  STAGE_B(0, 0, 0);
  STAGE_B(0, 1, 0);
  STAGE_A(0, 1, 0);

  const int nk = K / 64;                     // 16
  for (int t = 0; t < nk; t++) {
    int buf = t & 1, nbuf = buf ^ 1;
    int tn = (t < nk - 1) ? t + 1 : nk - 1;
    KTILE_BODY(buf, nbuf, tn);
  }
  asm volatile("s_waitcnt vmcnt(0)" ::: "memory");

#pragma unroll
  for (int i = 0; i < 8; i++) {
    int rb = bm + (i >> 2) * 128 + wm * 64 + (i & 3) * 16 + (lane >> 4) * 4;
#pragma unroll
    for (int r = 0; r < 4; r++) {
      int row = rb + r;
#pragma unroll
      for (int j = 0; j < 4; j++) {
        int col = bn + (j >> 1) * 128 + wn * 32 + (j & 1) * 16 + (lane & 15);
        out[(size_t)row * N + col] = acc[i][j][r] + bias[col];
      }
    }
  }
}

extern "C" void kernel_launch(void* const* d_in, const int* in_sizes, int n_in,
                              void* d_out, int out_size, void* d_ws, size_t ws_size,
                              hipStream_t stream) {
  const float* x      = (const float*)d_in[0];
  // d_in[1..4] = Wq, bq, Wk, bk — unused by the reference
  const float* Wv     = (const float*)d_in[5];
  const float* bv     = (const float*)d_in[6];
  const float* A_log  = (const float*)d_in[7];
  const float* A_bias = (const float*)d_in[8];
  const float* L      = (const float*)d_in[9];
  const float* Lb     = (const float*)d_in[10];
  const float* Wo     = (const float*)d_in[11];
  const float* bo     = (const float*)d_in[12];
  const int* levels   = (const int*)d_in[13];
  float* out = (float*)d_out;

  // workspace layout (bytes). Pw is UN-ALIASED (full 128 MiB span) so weights
  // can run concurrently with gemm_v; xb moved to outp's slot (xb dead before
  // attn writes outp — stream order makes the reuse safe).
  char* ws = (char*)d_ws;
  float* csT           = (float*)(ws + 0);                  // 128 KiB (cs, h-major)
  float* denom         = (float*)(ws + 131072);             // 128 KiB
  unsigned short* Wvb  = (unsigned short*)(ws + 262144);    // 2 MiB
  unsigned short* Wob  = (unsigned short*)(ws + 2359296);   // 2 MiB
  unsigned short* Pw   = (unsigned short*)(ws + 4456448);   // 128 MiB (no alias)
  unsigned short* vt   = (unsigned short*)(ws + 138674176); // 64 MiB
  unsigned short* xb   = (unsigned short*)(ws + 205783040); // 64 MiB (= outp slot)
  unsigned short* outp = (unsigned short*)(ws + 205783040); // 64 MiB (after xb dead)
  if (ws_size < 272891904ULL) return;

  // Stail scratch lives in the tail of d_out (512 KiB); gemm_out overwrites it
  // at the end; stream order k_tail -> k_gemm_attn -> k_gemm_out keeps it safe.
  float* Stail = out + (33554432 - 131072);  // out has 33,554,432 floats

  // 1) fused scan + cvts
  int npre = 16 + (NX4 + 2 * NW4) / 256;
  k_pre<<<npre, 256, 0, stream>>>(x, xb, Wv, Wvb, Wo, Wob, A_log, A_bias, csT);

  // 2) fused gemm_v + weights: [w,w,g] interleave, 3072 blocks x 512 threads
  k_gvw<<<3072, 512, 0, stream>>>(xb, Wvb, bv, vt, L, Lb, levels, csT, Pw, denom);

  // 3) v-suffix-sums
  k_tail<<<NHn * 1024, 256, 0, stream>>>(vt, Stail);

  // 4) attn GEMM (causal range + analytic tail)
  k_gemm_attn<<<dim3(8, 64), 512, 0, stream>>>(Pw, vt, denom, Stail, outp);

  // 5) output GEMM
  k_gemm_out<<<dim3(8, 64), 512, 0, stream>>>(outp, Wob, bo, out);
}

// Round 14
// 527.771 us; speedup vs baseline: 1.0517x; 1.0517x over previous
//
#include <hip/hip_runtime.h>
#include <stdint.h>

static constexpr int Bn = 16, Tn = 2048, En = 1024, NHn = 16, HDn = 64, NLEVn = 12;

typedef __attribute__((ext_vector_type(8))) short short8;
typedef __attribute__((ext_vector_type(4))) float floatx4;

__device__ __forceinline__ unsigned short f2bf(float f) {
  unsigned int u = __float_as_uint(f);
  u += 0x7fffu + ((u >> 16) & 1u);
  return (unsigned short)(u >> 16);
}
__device__ __forceinline__ float bf2f(unsigned short s) {
  return __uint_as_float(((unsigned int)s) << 16);
}

__device__ __forceinline__ void async16(const unsigned short* g, unsigned short* l) {
  __builtin_amdgcn_global_load_lds(
      (const __attribute__((address_space(1))) unsigned int*)g,
      (__attribute__((address_space(3))) unsigned int*)l, 16, 0, 0);
}

// ---------------- fused pre-pass: scan (blocks 0..15) + all fp32->bf16 cvts ----------------
static constexpr int NX4 = Bn * Tn * En / 4;   // 8,388,608
static constexpr int NW4 = En * En / 4;        // 262,144

__global__ void k_pre(const float* __restrict__ x, unsigned short* __restrict__ xb,
                      const float* __restrict__ Wv, unsigned short* __restrict__ Wvb,
                      const float* __restrict__ Wo, unsigned short* __restrict__ Wob,
                      const float* __restrict__ A_log, const float* __restrict__ A_bias,
                      float* __restrict__ csT) {
  int blk = blockIdx.x;
  int tid = threadIdx.x;
  if (blk < 16) {
    int h = blk;
    __shared__ float part[256];
    float loc[8];
    float run = 0.f;
#pragma unroll
    for (int j = 0; j < 8; j++) {
      int t = tid * 8 + j;
      float xx = A_log[t * NHn + h] + A_bias[t * NHn + h];
      float ls = -log1pf(__expf(-xx));
      run += ls;
      loc[j] = run;
    }
    part[tid] = run;
    __syncthreads();
    for (int d = 1; d < 256; d <<= 1) {
      float v = (tid >= d) ? part[tid - d] : 0.f;
      __syncthreads();
      part[tid] += v;
      __syncthreads();
    }
    float off = (tid > 0) ? part[tid - 1] : 0.f;
#pragma unroll
    for (int j = 0; j < 8; j++) csT[(size_t)h * Tn + tid * 8 + j] = loc[j] + off;
    return;
  }
  int i = (blk - 16) * 256 + tid;
  const float* src;
  unsigned short* dst;
  int base;
  if (i < NX4) { src = x; dst = xb; base = 0; }
  else if (i < NX4 + NW4) { src = Wv; dst = Wvb; base = NX4; }
  else if (i < NX4 + 2 * NW4) { src = Wo; dst = Wob; base = NX4 + NW4; }
  else return;
  int k = i - base;
  float4 v = ((const float4*)src)[k];
  ushort4 o;
  o.x = f2bf(v.x); o.y = f2bf(v.y); o.z = f2bf(v.z); o.w = f2bf(v.w);
  ((ushort4*)dst)[k] = o;
}

// ---------------- fused weights (blocks 0..2047) + v-suffix-sums (blocks 2048+) ----------------
__global__ void k_wt(const float* __restrict__ L, const float* __restrict__ Lb,
                     const int* __restrict__ levels, const float* __restrict__ csT,
                     unsigned short* __restrict__ P, float* __restrict__ denom,
                     const unsigned short* __restrict__ vt, float* __restrict__ Stail) {
  int tid = threadIdx.x;
  if (blockIdx.x < Tn) {
    int t = blockIdx.x;
    __shared__ float Lrow[NHn * NLEVn];
    __shared__ float cst[NHn];
    __shared__ float dsum[NHn];
    if (tid < NHn * NLEVn) Lrow[tid] = L[t * NHn * NLEVn + tid] + Lb[t * NHn * NLEVn + tid];
    if (tid < NHn) { cst[tid] = csT[(size_t)tid * Tn + t]; dsum[tid] = 0.f; }
    __syncthreads();
    int Bt = ((t >> 8) + 1) << 8;
    float acc[NHn];
#pragma unroll
    for (int h = 0; h < NHn; h++) acc[h] = 0.f;
    for (int s = tid; s < Bt; s += 256) {
      int lev = levels[(size_t)t * Tn + s];
      bool causal = (s <= t);
#pragma unroll
      for (int h = 0; h < NHn; h++) {
        float w = 1.f;   // exp(0) for s > t
        if (causal) {
          float csr = csT[(size_t)h * Tn + s];      // coalesced: 4 B/lane
          float dec = __expf(cst[h] - csr);
          w = __expf(Lrow[h * NLEVn + lev] * dec);
        }
        unsigned short pb = f2bf(w);
        acc[h] += bf2f(pb);
        P[((size_t)h * Tn + t) * Tn + s] = pb;
      }
    }
    int lane = tid & 63;
#pragma unroll
    for (int h = 0; h < NHn; h++) {
      float v = acc[h];
      for (int o = 32; o > 0; o >>= 1) v += __shfl_down(v, o, 64);
      if (lane == 0) atomicAdd(&dsum[h], v);
    }
    __syncthreads();
    if (tid < NHn) denom[(size_t)tid * Tn + t] = dsum[tid] + (float)(Tn - Bt);
  } else {
    int row = blockIdx.x - Tn;     // h*1024 + col, col=(b<<6)|d
    __shared__ float C[8];
    short8 v = *(const short8*)&vt[(size_t)row * Tn + tid * 8];
    float p = 0.f;
#pragma unroll
    for (int e = 0; e < 8; e++) p += bf2f((unsigned short)v[e]);
#pragma unroll
    for (int o = 16; o > 0; o >>= 1) p += __shfl_xor(p, o, 64);
    if ((tid & 31) == 0) C[tid >> 5] = p;
    __syncthreads();
    if (tid < 8) {
      float s = 0.f;
      for (int k = tid + 1; k < 8; k++) s += C[k];
      int h = row >> 10, col = row & 1023;
      Stail[(size_t)h * 8192 + tid * 1024 + col] = s;
    }
  }
}

// ================= GEMM 1: v = x@Wv^T + bv, 256x128 block, fused transpose =================
// (round-0 proven version: 48 KiB LDS, 2 blocks/CU)
__global__ __launch_bounds__(512)
void k_gemm_v(const unsigned short* __restrict__ A, const unsigned short* __restrict__ Bm,
              const float* __restrict__ bias, unsigned short* __restrict__ vt) {
  __shared__ unsigned short smem[24576];     // 48 KB: As(32K) | Bs(16K); epilogue reuses as Ct
  unsigned short* As = smem;                 // 256 x 64
  unsigned short* Bs = smem + 16384;         // 128 x 64
  const int K = 1024;
  int tid = threadIdx.x;
  int wave = tid >> 6, lane = tid & 63;
  int wm = wave >> 1, wn = wave & 1;         // 4 x 2 waves of 64x64 tiles

  int flat = blockIdx.y * 8 + blockIdx.x;    // gridDim.x == 8
  int xcd = flat & 7, slot = flat >> 3;      // slot 0..127
  int strip = xcd * 16 + (slot >> 3);        // 128 strips, 16 per XCD
  int nt = slot & 7;
  int bm = strip * 256, bn = nt * 128;

  floatx4 zero4 = {0.f, 0.f, 0.f, 0.f};
  floatx4 acc[4][4];
#pragma unroll
  for (int i = 0; i < 4; i++)
#pragma unroll
    for (int j = 0; j < 4; j++) acc[i][j] = zero4;

  for (int k0 = 0; k0 < K; k0 += 64) {
    __syncthreads();
#pragma unroll
    for (int j = 0; j < 4; j++) {            // A: 256 rows x 64 k (32KB)
      int f = j * 512 + tid;
      int r = f >> 3, c = f & 7;
      int cg = c ^ (r & 7);
      async16(&A[(size_t)(bm + r) * K + k0 + cg * 8], &As[f * 8]);
    }
#pragma unroll
    for (int j = 0; j < 2; j++) {            // B: 128 rows x 64 k (16KB)
      int f = j * 512 + tid;
      int r = f >> 3, c = f & 7;
      int cg = c ^ (r & 7);
      async16(&Bm[(size_t)(bn + r) * K + k0 + cg * 8], &Bs[f * 8]);
    }
    __syncthreads();
#pragma unroll
    for (int kk = 0; kk < 2; kk++) {
      short8 af[4], bfr[4];
      int cgk = kk * 4 + (lane >> 4);
#pragma unroll
      for (int i = 0; i < 4; i++) {
        int m = wm * 64 + i * 16 + (lane & 15);
        af[i] = *(const short8*)&As[m * 64 + ((cgk ^ (m & 7)) * 8)];
        int n = wn * 64 + i * 16 + (lane & 15);
        bfr[i] = *(const short8*)&Bs[n * 64 + ((cgk ^ (n & 7)) * 8)];
      }
#pragma unroll
      for (int i = 0; i < 4; i++)
#pragma unroll
        for (int j = 0; j < 4; j++)
          acc[i][j] = __builtin_amdgcn_mfma_f32_16x16x32_bf16(af[i], bfr[j], acc[i][j], 0, 0, 0);
    }
  }

  // ---- fused transpose epilogue: write vt[h][b][d][t] ----
  int b = bm >> 11, t0 = bm & 2047;
  unsigned short* Ct = smem;                 // 64 cols x (256+8) rows
  const int S = 264;
#pragma unroll 1
  for (int pass = 0; pass < 2; pass++) {
    __syncthreads();
    if (wn == pass) {
#pragma unroll
      for (int i = 0; i < 4; i++) {
#pragma unroll
        for (int j = 0; j < 4; j++) {
          int colL = j * 16 + (lane & 15);
          float bia = bias[bn + pass * 64 + colL];
          int rowb = wm * 64 + i * 16 + (lane >> 4) * 4;
          ushort4 p;
          p.x = f2bf(acc[i][j][0] + bia);
          p.y = f2bf(acc[i][j][1] + bia);
          p.z = f2bf(acc[i][j][2] + bia);
          p.w = f2bf(acc[i][j][3] + bia);
          *(ushort4*)&Ct[colL * S + rowb] = p;
        }
      }
    }
    __syncthreads();
#pragma unroll
    for (int cc = 0; cc < 4; cc++) {
      int colL = wave * 8 + cc * 2 + (lane >> 5);
      int gc = bn + pass * 64 + colL;
      int h = gc >> 6, d = gc & 63;
      int tt = (lane & 31) * 8;
      short8 v = *(const short8*)&Ct[colL * S + tt];
      *(short8*)&vt[((size_t)((h * Bn + b) * HDn + d)) * Tn + t0 + tt] = v;
    }
  }
}

// ================= shared 256x256 BK=64 macros (round-2 verified) =================

#define STAGE_A(kt, half, buf)                                                   \
  {                                                                              \
    _Pragma("unroll")                                                            \
    for (int j_ = 0; j_ < 2; j_++) {                                             \
      int f_ = j_ * 512 + tid;                                                   \
      int r_ = f_ >> 3, c_ = f_ & 7;                                             \
      int cg_ = c_ ^ (r_ & 7);                                                   \
      async16(&Ap[(size_t)(bm + (half) * 128 + r_) * K + (kt) * 64 + cg_ * 8],   \
              &smem[(buf) * 32768 + ((half) * 128 + r_) * 64 + c_ * 8]);         \
    }                                                                            \
  }

#define STAGE_B(kt, half, buf)                                                   \
  {                                                                              \
    _Pragma("unroll")                                                            \
    for (int j_ = 0; j_ < 2; j_++) {                                             \
      int f_ = j_ * 512 + tid;                                                   \
      int r_ = f_ >> 3, c_ = f_ & 7;                                             \
      int cg_ = c_ ^ (r_ & 7);                                                   \
      async16(&Bp[(size_t)(bn + (half) * 128 + r_) * K + (kt) * 64 + cg_ * 8],   \
              &smem[(buf) * 32768 + 16384 + ((half) * 128 + r_) * 64 + c_ * 8]); \
    }                                                                            \
  }

#define LOAD_A(buf, Mh)                                                          \
  {                                                                              \
    _Pragma("unroll")                                                            \
    for (int ii_ = 0; ii_ < 4; ii_++) {                                          \
      int m_ = (Mh) * 128 + wm * 64 + ii_ * 16 + (lane & 15);                    \
      _Pragma("unroll")                                                          \
      for (int kk_ = 0; kk_ < 2; kk_++) {                                        \
        int cgk_ = kk_ * 4 + (lane >> 4);                                        \
        aR[ii_][kk_] =                                                           \
            *(const short8*)&smem[(buf) * 32768 + m_ * 64 + ((cgk_ ^ (m_ & 7)) * 8)]; \
      }                                                                          \
    }                                                                            \
  }

#define LOAD_B(buf, Nh)                                                          \
  {                                                                              \
    _Pragma("unroll")                                                            \
    for (int jj_ = 0; jj_ < 2; jj_++) {                                          \
      int n_ = (Nh) * 128 + wn * 32 + jj_ * 16 + (lane & 15);                    \
      _Pragma("unroll")                                                          \
      for (int kk_ = 0; kk_ < 2; kk_++) {                                        \
        int cgk_ = kk_ * 4 + (lane >> 4);                                        \
        bR[jj_][kk_] = *(const short8*)&smem[(buf) * 32768 + 16384 + n_ * 64 +   \
                                             ((cgk_ ^ (n_ & 7)) * 8)];           \
      }                                                                          \
    }                                                                            \
  }

#define MFMA16(Mh, Nh)                                                           \
  {                                                                              \
    __builtin_amdgcn_s_setprio(1);                                               \
    _Pragma("unroll")                                                            \
    for (int kk_ = 0; kk_ < 2; kk_++)                                            \
      _Pragma("unroll")                                                          \
      for (int ii_ = 0; ii_ < 4; ii_++)                                          \
        _Pragma("unroll")                                                        \
        for (int jj_ = 0; jj_ < 2; jj_++)                                        \
          acc[(Mh) * 4 + ii_][(Nh) * 2 + jj_] = __builtin_amdgcn_mfma_f32_16x16x32_bf16( \
              aR[ii_][kk_], bR[jj_][kk_], acc[(Mh) * 4 + ii_][(Nh) * 2 + jj_], 0, 0, 0); \
    __builtin_amdgcn_s_setprio(0);                                               \
  }

#define WAIT6 asm volatile("s_waitcnt vmcnt(6)" ::: "memory")
#define BAR                                                                      \
  {                                                                              \
    asm volatile("" ::: "memory");                                               \
    __builtin_amdgcn_s_barrier();                                                \
    asm volatile("" ::: "memory");                                               \
  }

#define KTILE_BODY(buf, nbuf, tn)                                                \
  {                                                                              \
    STAGE_A(tn, 0, nbuf);                                                        \
    WAIT6; BAR;                                                                  \
    LOAD_A(buf, 0);                                                              \
    LOAD_B(buf, 0);                                                              \
    MFMA16(0, 0);                                                                \
    BAR;                                                                         \
    STAGE_B(tn, 0, nbuf);                                                        \
    WAIT6; BAR;                                                                  \
    LOAD_B(buf, 1);                                                              \
    MFMA16(0, 1);                                                                \
    BAR;                                                                         \
    STAGE_B(tn, 1, nbuf);                                                        \
    WAIT6; BAR;                                                                  \
    LOAD_A(buf, 1);                                                              \
    MFMA16(1, 1);                                                                \
    BAR;                                                                         \
    STAGE_A(tn, 1, nbuf);                                                        \
    WAIT6; BAR;                                                                  \
    LOAD_B(buf, 0);                                                              \
    MFMA16(1, 0);                                                                \
    BAR;                                                                         \
  }

// ================= GEMM 2: attn @ v, deterministic pair-balanced =================
// 256 blocks (1/CU); each block computes TWO row-bands sequentially:
// mt0 and 7-mt0 -> exactly 4(mt0+1)+4(8-mt0) = 36 K-tiles per block,
// uniform by construction (no reliance on dispatch order).
__global__ __launch_bounds__(512, 2)
void k_gemm_attn(const unsigned short* __restrict__ P, const unsigned short* __restrict__ vt,
                 const float* __restrict__ denom, const float* __restrict__ Stail,
                 unsigned short* __restrict__ outp) {
  __shared__ unsigned short smem[65536];     // 128 KiB: 2 x (A 256x64 | B 256x64)
  const int K = Tn;
  int tid = threadIdx.x;
  int wave = tid >> 6, lane = tid & 63;
  int wm = wave >> 2, wn = wave & 3;         // per-quadrant: 2x4 waves of 64x32

  int flat = blockIdx.y * 8 + blockIdx.x;    // gridDim = (8, 32)
  int xcd = flat & 7, slot = flat >> 3;      // slot 0..31 within XCD
  int h = xcd * 2 + (slot >> 4);             // 2 heads per XCD
  int sub = slot & 15;
  int mt0 = sub >> 2, nt = sub & 3;
  int bn = nt * 256;

  const unsigned short* Ap = P + (size_t)h * Tn * Tn;
  const unsigned short* Bp = vt + (size_t)h * (Bn * HDn) * Tn;

  floatx4 zero4 = {0.f, 0.f, 0.f, 0.f};
  floatx4 acc[8][4];
  short8 aR[4][2], bR[2][2];

#pragma unroll 1
  for (int ph = 0; ph < 2; ph++) {
    int mt = ph ? (7 - mt0) : mt0;
    int bm = mt * 256;

#pragma unroll
    for (int i = 0; i < 8; i++)
#pragma unroll
      for (int j = 0; j < 4; j++) acc[i][j] = zero4;

    // prologue: stage K-tile 0 into buf0 (same order as steady state)
    STAGE_A(0, 0, 0);
    STAGE_B(0, 0, 0);
    STAGE_B(0, 1, 0);
    STAGE_A(0, 1, 0);

    const int nkb = 4 * (mt + 1);            // causal K-tiles only
    for (int t = 0; t < nkb; t++) {
      int buf = t & 1, nbuf = buf ^ 1;
      int tn = (t < nkb - 1) ? t + 1 : nkb - 1;  // clamp (restage harmless)
      KTILE_BODY(buf, nbuf, tn);
    }
    // drain this thread's stage queue; epilogue uses only registers + global
    asm volatile("s_waitcnt vmcnt(0)" ::: "memory");

    float tl[4];
#pragma unroll
    for (int j = 0; j < 4; j++) {
      int col = bn + (j >> 1) * 128 + wn * 32 + (j & 1) * 16 + (lane & 15);
      tl[j] = Stail[(size_t)h * 8192 + mt * 1024 + col];
    }

#pragma unroll
    for (int i = 0; i < 8; i++) {
      int rb = bm + (i >> 2) * 128 + wm * 64 + (i & 3) * 16 + (lane >> 4) * 4;
#pragma unroll
      for (int r = 0; r < 4; r++) {
        int row = rb + r;
        float sc = 1.f / denom[(size_t)h * Tn + row];
#pragma unroll
        for (int j = 0; j < 4; j++) {
          int col = bn + (j >> 1) * 128 + wn * 32 + (j & 1) * 16 + (lane & 15);
          int b = col >> 6, d = col & 63;
          outp[((size_t)(b * Tn + row)) * En + h * HDn + d] = f2bf((acc[i][j][r] + tl[j]) * sc);
        }
      }
    }
    // all threads drained (each passed its own vmcnt(0) before this barrier),
    // so phase 2 may restage buf0 safely.
    BAR;
  }
}

// ================= GEMM 3: out = o@Wo^T + bo, 256x256 block (round-2 skeleton) =================
__global__ __launch_bounds__(512, 2)
void k_gemm_out(const unsigned short* __restrict__ A, const unsigned short* __restrict__ Bm,
                const float* __restrict__ bias, float* __restrict__ out) {
  __shared__ unsigned short smem[65536];     // 128 KiB
  const int K = 1024, N = 1024;
  int tid = threadIdx.x;
  int wave = tid >> 6, lane = tid & 63;
  int wm = wave >> 2, wn = wave & 3;

  int flat = blockIdx.y * 8 + blockIdx.x;    // gridDim = (8, 64)
  int wg = (flat & 7) * 64 + (flat >> 3);    // 512 blocks: 128 mt x 4 nt
  int mt = wg >> 2, nt = wg & 3;
  int bm = mt * 256, bn = nt * 256;

  const unsigned short* Ap = A;
  const unsigned short* Bp = Bm;

  floatx4 zero4 = {0.f, 0.f, 0.f, 0.f};
  floatx4 acc[8][4];
#pragma unroll
  for (int i = 0; i < 8; i++)
#pragma unroll
    for (int j = 0; j < 4; j++) acc[i][j] = zero4;

  short8 aR[4][2], bR[2][2];

  STAGE_A(0, 0, 0);
  STAGE_B(0, 0, 0);
  STAGE_B(0, 1, 0);
  STAGE_A(0, 1, 0);

  const int nk = K / 64;                     // 16
  for (int t = 0; t < nk; t++) {
    int buf = t & 1, nbuf = buf ^ 1;
    int tn = (t < nk - 1) ? t + 1 : nk - 1;
    KTILE_BODY(buf, nbuf, tn);
  }
  asm volatile("s_waitcnt vmcnt(0)" ::: "memory");

#pragma unroll
  for (int i = 0; i < 8; i++) {
    int rb = bm + (i >> 2) * 128 + wm * 64 + (i & 3) * 16 + (lane >> 4) * 4;
#pragma unroll
    for (int r = 0; r < 4; r++) {
      int row = rb + r;
#pragma unroll
      for (int j = 0; j < 4; j++) {
        int col = bn + (j >> 1) * 128 + wn * 32 + (j & 1) * 16 + (lane & 15);
        out[(size_t)row * N + col] = acc[i][j][r] + bias[col];
      }
    }
  }
}

extern "C" void kernel_launch(void* const* d_in, const int* in_sizes, int n_in,
                              void* d_out, int out_size, void* d_ws, size_t ws_size,
                              hipStream_t stream) {
  const float* x      = (const float*)d_in[0];
  // d_in[1..4] = Wq, bq, Wk, bk — unused by the reference
  const float* Wv     = (const float*)d_in[5];
  const float* bv     = (const float*)d_in[6];
  const float* A_log  = (const float*)d_in[7];
  const float* A_bias = (const float*)d_in[8];
  const float* L      = (const float*)d_in[9];
  const float* Lb     = (const float*)d_in[10];
  const float* Wo     = (const float*)d_in[11];
  const float* bo     = (const float*)d_in[12];
  const int* levels   = (const int*)d_in[13];
  float* out = (float*)d_out;

  // workspace layout (bytes); Pw aliases xb (dead after k_gemm_v) — round-12 proven
  char* ws = (char*)d_ws;
  float* csT           = (float*)(ws + 0);                  // 128 KiB (cs, h-major)
  float* denom         = (float*)(ws + 131072);             // 128 KiB
  unsigned short* Wvb  = (unsigned short*)(ws + 262144);    // 2 MiB
  unsigned short* Wob  = (unsigned short*)(ws + 2359296);   // 2 MiB
  unsigned short* xb   = (unsigned short*)(ws + 4456448);   // 64 MiB
  unsigned short* Pw   = (unsigned short*)(ws + 4456448);   // 128 MiB (aliases xb)
  unsigned short* vt   = (unsigned short*)(ws + 138674176); // 64 MiB
  unsigned short* outp = (unsigned short*)(ws + 205783040); // 64 MiB
  if (ws_size < 272891904ULL) return;

  // Stail scratch lives in the tail of d_out (512 KiB); gemm_out overwrites it
  // at the end; stream order k_wt -> k_gemm_attn -> k_gemm_out keeps it safe.
  float* Stail = out + (33554432 - 131072);  // out has 33,554,432 floats

  // 1) fused scan + cvts
  int npre = 16 + (NX4 + 2 * NW4) / 256;
  k_pre<<<npre, 256, 0, stream>>>(x, xb, Wv, Wvb, Wo, Wob, A_log, A_bias, csT);

  // 2) v-projection GEMM
  k_gemm_v<<<dim3(8, 128), 512, 0, stream>>>(xb, Wvb, bv, vt);

  // 3) fused weights + v-suffix-sums
  k_wt<<<Tn + NHn * 1024, 256, 0, stream>>>(L, Lb, levels, csT, Pw, denom, vt, Stail);

  // 4) attn GEMM (causal range + analytic tail, deterministic pair-balance)
  k_gemm_attn<<<dim3(8, 32), 512, 0, stream>>>(Pw, vt, denom, Stail, outp);

  // 5) output GEMM
  k_gemm_out<<<dim3(8, 64), 512, 0, stream>>>(outp, Wob, bo, out);
}